// Round 7
// baseline (60.709 us; speedup 1.0000x reference)
//
#include <hip/hip_runtime.h>

// SpikingConv2D: y = conv3x3_same(tj, W) + (1 - D_i[0,f]); out = min(y, 1.0), NHWC fp32.
// R6: sync-minimal patch-resident implicit GEMM.
//  - Block = 4 rows x 56 = 224 px, 4 waves, grid 448 (XCD-bijective), 48 KB LDS.
//  - A patch (10x58 px halo, 32-ch quarter) in LDS, double-buffered by quarter;
//    staged via global_load_lds at quarter start; drained by the end-of-quarter
//    __syncthreads() (implicit vmcnt(0)) -- issued ~9 taps earlier, so free.
//  - B (weights) NOT in LDS: fragments load straight from L2-resident Wt into
//    registers, prefetched one tap ahead. No per-tap sync at all.
//  - ONLY 4 barriers per kernel; 252-MFMA barrier-free regions let the compiler
//    software-pipeline ds_reads + B-loads under MFMAs (R5's cross-wave vmcnt race
//    is structurally impossible: every LDS consumer is separated from its producer
//    by a full __syncthreads drain).
//  - A granule XOR-swizzle swz(g)=g^((g>>3)&3), applied to staging source AND read
//    address (involution): fragment reads (lane stride 4 granules) spread from
//    8-way to 2-way bank conflict (free).

#define BZ 32
#define CC 128
#define HH 56
#define WWD 56
#define HWP 3136
#define FF 128
#define PH 58
#define PW 58
#define AB_BYTES 24576      // per A buffer: 1536 granules * 16 B (1392 real)
#define A_GRAN_REAL 1392    // 6 rows * 58 px * 4 granules

typedef __attribute__((ext_vector_type(8))) __bf16 bf16x8;
typedef __attribute__((ext_vector_type(4))) float f32x4;
typedef __attribute__((ext_vector_type(8))) unsigned short us8;
typedef __attribute__((ext_vector_type(4))) float flt4;

__device__ __forceinline__ unsigned short f2bf(float f) {
  unsigned int u = __float_as_uint(f);
  unsigned int r = (u + 0x7FFFu + ((u >> 16) & 1u)) >> 16;
  return (unsigned short)r;
}

#define GLOAD_LDS16(g, l)                                                              \
  __builtin_amdgcn_global_load_lds((const __attribute__((address_space(1))) void*)(g), \
                                   (__attribute__((address_space(3))) void*)(l), 16, 0, 0)

// ---- W repack (linear): Wt slice S=q*9+r, granule g=f*4+kg holds channels
//      q*32+kg*8..+8 of filter f, tap r. 512 granules (8 KB) per slice. ----
__global__ void prep_w_kernel(const float* __restrict__ W, unsigned short* __restrict__ Wt) {
  int idx = blockIdx.x * 256 + threadIdx.x;
  if (idx >= 36 * 512) return;
  int qr = idx >> 9;
  int g = idx & 511;
  int q = qr / 9, r = qr - q * 9;
  int f = g >> 2, kg = g & 3;
  us8 v;
#pragma unroll
  for (int j = 0; j < 8; ++j) {
    int c = q * 32 + kg * 8 + j;
    v[j] = f2bf(W[(c * 9 + r) * FF + f]);
  }
  *reinterpret_cast<us8*>(Wt + (size_t)idx * 8) = v;
}

// ---- image prepass: x NCHW f32 -> xp padded NHWC bf16 [B][58][58][128] ----
__global__ __launch_bounds__(256) void prep_x_kernel(const float* __restrict__ x,
                                                     unsigned short* __restrict__ xp) {
  const int blk = blockIdx.x;
  const int b = blk / PH;
  const int ph = blk - b * PH;
  const int tid = threadIdx.x;
  unsigned short* dst = xp + (size_t)(b * PH + ph) * PW * CC;

  if (ph == 0 || ph == PH - 1) {
    us8 z;
#pragma unroll
    for (int k = 0; k < 8; ++k) z[k] = 0;
    for (int i = tid; i < PW * CC / 8; i += 256) reinterpret_cast<us8*>(dst)[i] = z;
    return;
  }

  __shared__ float sm[CC][57];
  const int h = ph - 1;
  {
    const int c = tid >> 1;
    const int half = tid & 1;
    const float* src = x + ((size_t)(b * CC + c)) * HWP + h * WWD + half * 28;
#pragma unroll
    for (int k = 0; k < 7; ++k) {
      flt4 v = *reinterpret_cast<const flt4*>(src + k * 4);
      sm[c][half * 28 + k * 4 + 0] = v[0];
      sm[c][half * 28 + k * 4 + 1] = v[1];
      sm[c][half * 28 + k * 4 + 2] = v[2];
      sm[c][half * 28 + k * 4 + 3] = v[3];
    }
  }
  __syncthreads();
  for (int i = tid; i < PW * 16; i += 256) {
    const int ww = i >> 4;
    const int cg = i & 15;
    us8 v;
    if (ww == 0 || ww == PW - 1) {
#pragma unroll
      for (int k = 0; k < 8; ++k) v[k] = 0;
    } else {
      const int w = ww - 1;
#pragma unroll
      for (int k = 0; k < 8; ++k) v[k] = f2bf(sm[cg * 8 + k][w]);
    }
    reinterpret_cast<us8*>(dst)[i] = v;
  }
}

// ---------------- main kernel ----------------
__global__ __launch_bounds__(256, 2) void spiking_conv_main(
    const unsigned short* __restrict__ xp, const unsigned short* __restrict__ Wt,
    const float* __restrict__ Di, float* __restrict__ out) {
  __shared__ unsigned char lds[2 * AB_BYTES];  // 48 KB

  const int bid = blockIdx.x;
  const int wg = (bid & 7) * 56 + (bid >> 3);  // 448 = 56 per XCD, bijective
  const int b = wg / 14;
  const int rg = wg - b * 14;
  const int h0 = rg * 4;

  const int tid = threadIdx.x;
  const int lane = tid & 63, wv = tid >> 6;
  const int wr = wv >> 1, wc = wv & 1;
  const int frow = lane & 15, kg = lane >> 4;

  // A staging source offsets (quarter-0 channel base; swizzle baked into source).
  int srcA[6];
#pragma unroll
  for (int k = 0; k < 6; ++k) {
    int gp = k * 256 + tid;
    int g = (gp >= A_GRAN_REAL) ? 0 : (gp ^ ((gp >> 3) & 3));
    int prow = g / 232;  // patch row (58 px * 4 granules)
    int rem = g - prow * 232;
    int px = rem >> 2;
    int kg2 = rem & 3;
    srcA[k] = ((b * PH + h0 + prow) * PW + px) * CC + kg2 * 8;
  }
  // A-fragment logical granule (dh=dw=0) per M-frag.
  int gbase[7];
#pragma unroll
  for (int i = 0; i < 7; ++i) {
    int t = 16 * i + frow;  // 0..111 within wave's 112-px half
    int rowb = (t >= 56) ? 1 : 0;
    int col = t - 56 * rowb;
    gbase[i] = ((2 * wr + rowb + 1) * PW + (col + 1)) * 4 + kg;
  }
  // B-fragment granule base: filter = wc*64 + 16j + frow, j adds 64 granules.
  const int gB = (wc * 64 + frow) * 4 + kg;

  f32x4 acc[7][4];
  const f32x4 zero = {0.0f, 0.0f, 0.0f, 0.0f};
#pragma unroll
  for (int i = 0; i < 7; ++i)
#pragma unroll
    for (int j = 0; j < 4; ++j) acc[i][j] = zero;

  // prologue: stage A quarter 0 into buf 0; __syncthreads drains (vmcnt(0)).
#pragma unroll
  for (int k = 0; k < 6; ++k)
    GLOAD_LDS16(xp + srcA[k], lds + (size_t)(k * 256 + tid) * 16);
  __syncthreads();

#pragma unroll
  for (int q = 0; q < 4; ++q) {
    // issue next quarter's A staging early -- drained by end-of-quarter sync.
    if (q < 3) {
#pragma unroll
      for (int k = 0; k < 6; ++k)
        GLOAD_LDS16(xp + srcA[k] + (q + 1) * 32,
                    lds + ((q + 1) & 1) * AB_BYTES + (size_t)(k * 256 + tid) * 16);
    }
    const unsigned char* pa = lds + (q & 1) * AB_BYTES;
    const unsigned short* ws = Wt + (size_t)(q * 9) * 4096;

    bf16x8 bcur[4], bnext[4];
#pragma unroll
    for (int j = 0; j < 4; ++j)
      bcur[j] = *reinterpret_cast<const bf16x8*>(ws + (size_t)(gB + j * 64) * 8);

#pragma unroll
    for (int r = 0; r < 9; ++r) {
      if (r < 8) {
#pragma unroll
        for (int j = 0; j < 4; ++j)
          bnext[j] = *reinterpret_cast<const bf16x8*>(
              ws + (size_t)(r + 1) * 4096 + (size_t)(gB + j * 64) * 8);
      }
      const int dh = r / 3 - 1, dw = r - (r / 3) * 3 - 1;
      const int tapoff = (dh * PW + dw) * 4;
      bf16x8 af[7];
#pragma unroll
      for (int i = 0; i < 7; ++i) {
        int gt = gbase[i] + tapoff;
        af[i] = *reinterpret_cast<const bf16x8*>(pa + ((gt ^ ((gt >> 3) & 3)) << 4));
      }
#pragma unroll
      for (int i = 0; i < 7; ++i)
#pragma unroll
        for (int j = 0; j < 4; ++j)
          acc[i][j] = __builtin_amdgcn_mfma_f32_16x16x32_bf16(af[i], bcur[j], acc[i][j], 0, 0, 0);
      if (r < 8) {
#pragma unroll
        for (int j = 0; j < 4; ++j) bcur[j] = bnext[j];
      }
    }
    if (q < 3) __syncthreads();  // drains A[q+1] staging + syncs buffer swap
  }

  // epilogue: + (1 - D_i[f]), clamp 1.0, NHWC fp32
#pragma unroll
  for (int j = 0; j < 4; ++j) {
    const int col = wc * 64 + 16 * j + frow;
    const float thr = 1.0f - Di[col];
#pragma unroll
    for (int i = 0; i < 7; ++i) {
      const int bt = 16 * i + kg * 4;  // 4-run never crosses the 56 boundary
      const int rowb = (bt >= 56) ? 1 : 0;
      const int wl0 = bt - 56 * rowb;
      const int orow = h0 + 2 * wr + rowb;
      const size_t obase = ((size_t)b * HWP + (size_t)orow * WWD + wl0) * FF + col;
#pragma unroll
      for (int qq = 0; qq < 4; ++qq) {
        float v = acc[i][j][qq] + thr;
        out[obase + (size_t)qq * FF] = fminf(v, 1.0f);
      }
    }
  }
}

// ---- fallback (round-0 style, reads W directly) ----
__global__ __launch_bounds__(256) void spiking_conv_fallback(
    const float* __restrict__ x, const float* __restrict__ Wf,
    const float* __restrict__ Di, float* __restrict__ out) {
  __shared__ unsigned short Asm2[128][32];
  __shared__ unsigned short Bsm2[128][32];
  const int tid = threadIdx.x;
  const int m0 = blockIdx.x * 128;
  const int mi = tid & 127;
  const int half = tid >> 7;
  const int m = m0 + mi;
  const int bimg = m / HWP;
  const int p = m - bimg * HWP;
  const int h = p / WWD;
  const int w = p - h * WWD;
  const int baseA = (bimg * CC) * HWP + h * WWD + w;
  const int lane = tid & 63;
  const int wid = tid >> 6;
  const int wr = wid >> 1;
  const int wc = wid & 1;
  const int frow = lane & 15;
  const int kg = lane >> 4;
  f32x4 acc[4][4];
  const f32x4 zero = {0.0f, 0.0f, 0.0f, 0.0f};
#pragma unroll
  for (int i = 0; i < 4; ++i)
#pragma unroll
    for (int j = 0; j < 4; ++j) acc[i][j] = zero;
  for (int r = 0; r < 9; ++r) {
    const int dh = r / 3 - 1;
    const int dw = r - (r / 3) * 3 - 1;
    const int hh = h + dh;
    const int ww2 = w + dw;
    const bool valid = ((unsigned)hh < (unsigned)HH) && ((unsigned)ww2 < (unsigned)WWD);
    const int aoff2 = baseA + dh * WWD + dw + half * 16 * HWP;
    for (int c0 = 0; c0 < CC; c0 += 32) {
      __syncthreads();
      {
        const float* src = x + aoff2 + c0 * HWP;
        us8 v0, v1;
#pragma unroll
        for (int i = 0; i < 8; ++i) {
          float f0 = valid ? src[i * HWP] : 0.0f;
          float f1 = valid ? src[(i + 8) * HWP] : 0.0f;
          v0[i] = f2bf(f0);
          v1[i] = f2bf(f1);
        }
        *reinterpret_cast<us8*>(&Asm2[mi][half * 16]) = v0;
        *reinterpret_cast<us8*>(&Asm2[mi][half * 16 + 8]) = v1;
      }
      {
        us8 v0, v1;
#pragma unroll
        for (int i = 0; i < 8; ++i) {
          int cc2 = c0 + half * 16 + i;
          v0[i] = f2bf(Wf[(cc2 * 9 + r) * FF + mi]);
          v1[i] = f2bf(Wf[((cc2 + 8) * 9 + r) * FF + mi]);
        }
        *reinterpret_cast<us8*>(&Bsm2[mi][half * 16]) = v0;
        *reinterpret_cast<us8*>(&Bsm2[mi][half * 16 + 8]) = v1;
      }
      __syncthreads();
      bf16x8 af[4], bfr[4];
#pragma unroll
      for (int i = 0; i < 4; ++i)
        af[i] = *reinterpret_cast<const bf16x8*>(&Asm2[wr * 64 + i * 16 + frow][kg * 8]);
#pragma unroll
      for (int j = 0; j < 4; ++j)
        bfr[j] = *reinterpret_cast<const bf16x8*>(&Bsm2[wc * 64 + j * 16 + frow][kg * 8]);
#pragma unroll
      for (int i = 0; i < 4; ++i)
#pragma unroll
        for (int j = 0; j < 4; ++j)
          acc[i][j] = __builtin_amdgcn_mfma_f32_16x16x32_bf16(af[i], bfr[j], acc[i][j], 0, 0, 0);
    }
  }
#pragma unroll
  for (int j = 0; j < 4; ++j) {
    const int col = wc * 64 + j * 16 + frow;
    const float thr = 1.0f - Di[col];
#pragma unroll
    for (int i = 0; i < 4; ++i) {
      const int rbase = m0 + wr * 64 + i * 16 + kg * 4;
#pragma unroll
      for (int qq = 0; qq < 4; ++qq) {
        float v = acc[i][j][qq] + thr;
        out[(size_t)(rbase + qq) * FF + col] = fminf(v, 1.0f);
      }
    }
  }
}

extern "C" void kernel_launch(void* const* d_in, const int* in_sizes, int n_in,
                              void* d_out, int out_size, void* d_ws, size_t ws_size,
                              hipStream_t stream) {
  const float* tj = (const float*)d_in[0];
  const float* W = (const float*)d_in[1];
  const float* Di = (const float*)d_in[2];
  float* out = (float*)d_out;

  const size_t wt_bytes = (size_t)36 * 512 * 16;           // 294912
  const size_t xp_bytes = (size_t)BZ * PH * PW * CC * 2;   // 27557888
  unsigned short* Wt = (unsigned short*)d_ws;
  unsigned short* xp = (unsigned short*)((char*)d_ws + wt_bytes);

  bool fast = (ws_size >= wt_bytes + xp_bytes);
  if (fast) {
    prep_w_kernel<<<72, 256, 0, stream>>>(W, Wt);
    prep_x_kernel<<<BZ * PH, 256, 0, stream>>>(tj, xp);
    spiking_conv_main<<<448, 256, 0, stream>>>(xp, Wt, Di, out);
    if (hipGetLastError() != hipSuccess) fast = false;
  }
  if (!fast) {
    spiking_conv_fallback<<<100352 / 128, 256, 0, stream>>>(tj, W, Di, out);
  }
}